// Round 4
// baseline (1385.031 us; speedup 1.0000x reference)
//
#include <hip/hip_runtime.h>
#include <hip/hip_bf16.h>
#include <hip/hip_fp16.h>
#include <cstdint>
#include <cstddef>

#define NB   131072   // items
#define ED   256      // e_dim
#define NQL  4        // levels
#define NEC  256      // codebook entries

typedef _Float16 f16;
typedef f16  f16x8 __attribute__((ext_vector_type(8)));
typedef float f32x4 __attribute__((ext_vector_type(4)));

static constexpr float FMAXV = 3.402823466e+38f;
static constexpr float TAU   = 0.15625f;   // rescore gate on approx top-2 gap

static constexpr size_t OFF_REC  = (size_t)NB * ED;
static constexpr size_t OFF_LOSS = 2 * (size_t)NB * ED;
static constexpr size_t OFF_SIDX = OFF_LOSS + 1;
static constexpr size_t OFF_RIDX = OFF_SIDX + (size_t)NB * NQL;

// workspace layout (bytes)
static constexpr size_t WS_LOSS = 0;                      // 8 doubles
static constexpr size_t WS_NORM = 256;                    // 8*256 f32 (norm - 256)
static constexpr size_t WS_CBH  = 256 + 8 * 256 * 4;      // 8448; 8*256*256 f16 (1 MB)

// ---- prep: zero loss accumulator + codebook row norms (pre-shifted by -256) ----
__global__ void kPrep(const float* __restrict__ cbS, const float* __restrict__ cbR,
                      float* __restrict__ norms, double* __restrict__ lossAcc) {
  const int cbi = blockIdx.x;    // 0..7
  const int j   = threadIdx.x;   // 0..255
  if (cbi == 0 && j < 8) lossAcc[j] = 0.0;
  const float* row = (cbi < 4 ? cbS : cbR) + ((size_t)(cbi & 3) * NEC + j) * ED;
  float acc = 0.f;
  for (int k = 0; k < ED; k += 4) {
    float4 v = *(const float4*)(row + k);
    acc += v.x * v.x + v.y * v.y + v.z * v.z + v.w * v.w;
  }
  norms[cbi * NEC + j] = acc - 256.0f;   // exact shift (Sterbenz range)
}

// ---- f16 copy of codebooks (natural [cbi][j][k] layout) ----
__global__ void kConvH(const float* __restrict__ cbS, const float* __restrict__ cbR,
                       f16* __restrict__ cbH) {
  const int f   = blockIdx.x * 256 + threadIdx.x;   // 0..524287
  const int cbi = f >> 16;
  const int rem = f & 65535;
  const float v = (cbi < 4 ? cbS + ((size_t)cbi << 16) : cbR + ((size_t)(cbi - 4) << 16))[rem];
  cbH[f] = (f16)v;   // RTN
}

// packed key helpers: low 8 mantissa bits carry the codeword index
__device__ __forceinline__ float pk(float v, int j) {
  return __uint_as_float((__float_as_uint(v) & ~255u) | (unsigned)j);
}
__device__ __forceinline__ float unpv(float k) {
  return __uint_as_float(__float_as_uint(k) & ~255u);
}
__device__ __forceinline__ void ins3(float& s0, float& s1, float& s2, float k) {
  float t0 = fmaxf(s0, k); s0 = fminf(s0, k);
  float t1 = fmaxf(s1, t0); s1 = fminf(s1, t0);
  s2 = fminf(s2, t1);
}
__device__ __forceinline__ void mrg3(float& a0, float& a1, float& a2,
                                     float b0, float b1, float b2) {
  float x  = fmaxf(a0, b0);
  float c0 = fminf(a0, b0);
  float m1 = fminf(a1, b1), M1 = fmaxf(a1, b1);
  float c1 = fminf(fminf(x, a1), b1);
  float c2 = fminf(fminf(fmaxf(x, m1), M1), fminf(a2, b2));
  a0 = c0; a1 = c1; a2 = c2;
}

// ---- main fused RVQ kernel: 64 items/block, res in registers, 4 blocks/CU ----
__global__ __launch_bounds__(256, 4)
void kMain(const float* __restrict__ x,
           const float* __restrict__ cbS,
           const float* __restrict__ cbR,
           const f16*  __restrict__ cbH,
           const float* __restrict__ norms,
           double* __restrict__ lossAcc,
           float* __restrict__ out) {
  __shared__ __align__(16) char  RhBuf[64 * 512];      // f16 residual image, swizzled (32 KB)
  __shared__ __align__(16) float keybuf[64][4][4];     // per-wave top-3 per item (4 KB)
  __shared__ float redS[4];

  const int tid   = threadIdx.x;
  const int lane  = tid & 63;
  const int w     = tid >> 6;       // wave: owns codewords [64w, 64w+64)
  const int it_o  = tid >> 2;       // owner item 0..63
  const int kq    = tid & 3;        // owner k-quarter
  const int b0    = blockIdx.x * 64;
  const int l15   = lane & 15;
  const int l4    = lane >> 4;

  float res[64];
  float lossReg = 0.f;

#pragma unroll 1
  for (int br = 0; br < 2; ++br) {
    const float* cbf32 = br ? cbR : cbS;

    // load residual = x[:, br*E .. br*E+E) slice into registers
    {
      const float* xp = x + (size_t)(b0 + it_o) * (2 * ED) + br * ED + kq * 64;
#pragma unroll
      for (int i = 0; i < 16; ++i) {
        float4 v = *(const float4*)(xp + 4 * i);
        res[4 * i + 0] = v.x; res[4 * i + 1] = v.y;
        res[4 * i + 2] = v.z; res[4 * i + 3] = v.w;
      }
    }

#pragma unroll 1
    for (int lev = 0; lev < NQL; ++lev) {
      const int cbi = br * 4 + lev;
      const float* nrm = norms + (size_t)cbi * NEC;

      // norm values for this wave's codeword columns (L1/L2-hot after level 0)
      float nv[4];
#pragma unroll
      for (int nt = 0; nt < 4; ++nt) nv[nt] = nrm[(w * 4 + nt) * 16 + l15];

      // convert res -> Rh (f16, RTN), swizzled rows of 512B
#pragma unroll
      for (int c = 0; c < 8; ++c) {
        f16x8 h;
#pragma unroll
        for (int u = 0; u < 8; ++u) h[u] = (f16)res[c * 8 + u];
        int off = it_o * 512 + kq * 128 + c * 16;
        off ^= (it_o & 7) << 4;
        *(f16x8*)&RhBuf[off] = h;
      }
      __syncthreads();   // barrier 1: Rh ready

      const f16* cbh = cbH + ((size_t)cbi << 16);

      // ---- GEMM + keys, one 16-item tile at a time (acc[4] live, not acc[4][4]) ----
#pragma unroll 1
      for (int mt = 0; mt < 4; ++mt) {
        f32x4 acc[4];
#pragma unroll
        for (int nt = 0; nt < 4; ++nt) { f32x4 z = {0.f, 0.f, 0.f, 0.f}; acc[nt] = z; }

        const int it = mt * 16 + l15;
#pragma unroll 2
        for (int ks = 0; ks < 8; ++ks) {
          // NOTE: XOR must be applied to the FULL offset (write side does the same);
          // hoisting it onto the base alone permutes k-slots for it&7 != 0.
          const int offA = (it * 512 + ks * 64 + l4 * 16) ^ ((it & 7) << 4);
          f16x8 A = *(const f16x8*)&RhBuf[offA];
          f16x8 Bf[4];
#pragma unroll
          for (int nt = 0; nt < 4; ++nt) {
            int j = (w * 4 + nt) * 16 + l15;
            Bf[nt] = *(const f16x8*)&cbh[(size_t)j * ED + ks * 32 + l4 * 8];
          }
#pragma unroll
          for (int nt = 0; nt < 4; ++nt)
            acc[nt] = __builtin_amdgcn_mfma_f32_16x16x32_f16(A, Bf[nt], acc[nt], 0, 0, 0);
        }

        // keys + in-wave top-3 butterfly over the 16 l15-lanes (j-dimension)
#pragma unroll
        for (int r = 0; r < 4; ++r) {
          float s0 = FMAXV, s1 = FMAXV, s2 = FMAXV;
#pragma unroll
          for (int nt = 0; nt < 4; ++nt) {
            int j = (w * 4 + nt) * 16 + l15;
            ins3(s0, s1, s2, pk(fmaf(-2.f, acc[nt][r], nv[nt]), j));
          }
#pragma unroll
          for (int off = 1; off < 16; off <<= 1) {
            float b0k = __shfl_xor(s0, off), b1k = __shfl_xor(s1, off), b2k = __shfl_xor(s2, off);
            mrg3(s0, s1, s2, b0k, b1k, b2k);
          }
          if (l15 == r) {   // one writer per (l4, r) item (all lanes hold same result)
            float4 v; v.x = s0; v.y = s1; v.z = s2; v.w = FMAXV;
            *(float4*)&keybuf[mt * 16 + l4 * 4 + r][w][0] = v;
          }
        }
      }
      __syncthreads();   // barrier 2: keybuf ready (also: all GEMM reads of Rh done)

      // ---- cross-wave merge in the owner quad (no serial section, no LDS flags) ----
      int jm;
      {
        float4 v = *(const float4*)&keybuf[it_o][kq][0];
        float s0 = v.x, s1 = v.y, s2 = v.z;
        {
          float b0k = __shfl_xor(s0, 1), b1k = __shfl_xor(s1, 1), b2k = __shfl_xor(s2, 1);
          mrg3(s0, s1, s2, b0k, b1k, b2k);
          b0k = __shfl_xor(s0, 2); b1k = __shfl_xor(s1, 2); b2k = __shfl_xor(s2, 2);
          mrg3(s0, s1, s2, b0k, b1k, b2k);
        }
        jm = (int)(__float_as_uint(s0) & 255u);
        const float gap = unpv(s1) - unpv(s0);
        if (gap < TAU) {   // quad-uniform branch: exact fp32 rescore of top-3
          const int cand[3] = { jm,
                                (int)(__float_as_uint(s1) & 255u),
                                (int)(__float_as_uint(s2) & 255u) };
          float bestd = FMAXV; int bestj = 0;
#pragma unroll 1
          for (int cc = 0; cc < 3; ++cc) {
            const int j = cand[cc];
            const float* row = cbf32 + ((size_t)lev * NEC + j) * ED + kq * 64;
            float p = 0.f;
#pragma unroll
            for (int i = 0; i < 16; ++i) {
              float4 q = *(const float4*)(row + 4 * i);
              p = fmaf(res[4 * i + 0], q.x, p);
              p = fmaf(res[4 * i + 1], q.y, p);
              p = fmaf(res[4 * i + 2], q.z, p);
              p = fmaf(res[4 * i + 3], q.w, p);
            }
            p += __shfl_xor(p, 1);
            p += __shfl_xor(p, 2);
            const float d = fmaf(-2.f, p, nrm[j]);
            if (d < bestd || (d == bestd && j < bestj)) { bestd = d; bestj = j; }
          }
          jm = bestj;
        }
        if (kq == 0) {
          const size_t ioff = (br ? OFF_RIDX : OFF_SIDX) + (size_t)(b0 + it_o) * NQL + lev;
          out[ioff] = (float)jm;
        }
      }

      // ---- residual update + loss (exact reference rounding chain) ----
      {
        const float* crow = cbf32 + ((size_t)lev * NEC + jm) * ED + kq * 64;
#pragma unroll
        for (int i = 0; i < 16; ++i) {
          float4 q = *(const float4*)(crow + 4 * i);
#pragma unroll
          for (int u = 0; u < 4; ++u) {
            float cv = (u == 0 ? q.x : u == 1 ? q.y : u == 2 ? q.z : q.w);
            float r  = res[4 * i + u];
            float dd = cv - r;
            lossReg = fmaf(dd, dd, lossReg);
            float xr = r + dd;      // straight-through x_res
            res[4 * i + u] = r - xr;
          }
        }
      }
    }

    // x_q = x - res_final
    {
      const float* xp = x + (size_t)(b0 + it_o) * (2 * ED) + br * ED + kq * 64;
      float* op = out + (br ? OFF_REC : 0) + (size_t)(b0 + it_o) * ED + kq * 64;
#pragma unroll
      for (int i = 0; i < 16; ++i) {
        float4 xv = *(const float4*)(xp + 4 * i);
        float4 o;
        o.x = xv.x - res[4 * i + 0];
        o.y = xv.y - res[4 * i + 1];
        o.z = xv.z - res[4 * i + 2];
        o.w = xv.w - res[4 * i + 3];
        *(float4*)(op + 4 * i) = o;
      }
    }
  }

  // ---- loss: one wave-reduce + one atomic per block, once per kernel ----
#pragma unroll
  for (int d = 1; d < 64; d <<= 1) lossReg += __shfl_xor(lossReg, d);
  if (lane == 0) redS[w] = lossReg;
  __syncthreads();
  if (tid == 0)
    atomicAdd(&lossAcc[0], (double)((redS[0] + redS[1]) + (redS[2] + redS[3])));
}

// ---- finalize scalar loss ----
__global__ void kFin(const double* __restrict__ lossAcc, float* __restrict__ out) {
  if (blockIdx.x == 0 && threadIdx.x == 0) {
    out[OFF_LOSS] = (float)(lossAcc[0] * 1.25 / ((double)NB * ED) / 8.0);
  }
}

extern "C" void kernel_launch(void* const* d_in, const int* in_sizes, int n_in,
                              void* d_out, int out_size, void* d_ws, size_t ws_size,
                              hipStream_t stream) {
  const float* x   = (const float*)d_in[0];
  const float* cbS = (const float*)d_in[1];
  const float* cbR = (const float*)d_in[2];
  float* out = (float*)d_out;
  char*  ws  = (char*)d_ws;

  double* lossAcc = (double*)(ws + WS_LOSS);
  float*  norms   = (float*)(ws + WS_NORM);
  f16*    cbH     = (f16*)(ws + WS_CBH);

  hipLaunchKernelGGL(kPrep,  dim3(8),    dim3(256), 0, stream, cbS, cbR, norms, lossAcc);
  hipLaunchKernelGGL(kConvH, dim3(2048), dim3(256), 0, stream, cbS, cbR, cbH);
  hipLaunchKernelGGL(kMain,  dim3(NB / 64), dim3(256), 0, stream,
                     x, cbS, cbR, cbH, norms, lossAcc, out);
  hipLaunchKernelGGL(kFin,   dim3(1),    dim3(64),  0, stream, lossAcc, out);
}

// Round 5
// 1215.994 us; speedup vs baseline: 1.1390x; 1.1390x over previous
//
#include <hip/hip_runtime.h>
#include <hip/hip_bf16.h>
#include <hip/hip_fp16.h>
#include <cstdint>
#include <cstddef>

#define NB   131072   // items
#define ED   256      // e_dim
#define NQL  4        // levels
#define NEC  256      // codebook entries

typedef _Float16 f16;
typedef f16  f16x8 __attribute__((ext_vector_type(8)));
typedef float f32x4 __attribute__((ext_vector_type(4)));

static constexpr float FMAXV = 3.402823466e+38f;
static constexpr float TAU   = 0.15625f;   // rescore gate on approx top-2 gap

static constexpr size_t OFF_REC  = (size_t)NB * ED;
static constexpr size_t OFF_LOSS = 2 * (size_t)NB * ED;
static constexpr size_t OFF_SIDX = OFF_LOSS + 1;
static constexpr size_t OFF_RIDX = OFF_SIDX + (size_t)NB * NQL;

// workspace layout (bytes)
static constexpr size_t WS_LOSS = 0;                      // 8 doubles
static constexpr size_t WS_NORM = 256;                    // 8*256 f32 (norm - 256)
static constexpr size_t WS_CBH  = 256 + 8 * 256 * 4;      // 8448; 8*256*256 f16 (1 MB)

// ---- prep: zero loss accumulator + codebook row norms (pre-shifted by -256) ----
__global__ void kPrep(const float* __restrict__ cbS, const float* __restrict__ cbR,
                      float* __restrict__ norms, double* __restrict__ lossAcc) {
  const int cbi = blockIdx.x;    // 0..7
  const int j   = threadIdx.x;   // 0..255
  if (cbi == 0 && j < 8) lossAcc[j] = 0.0;
  const float* row = (cbi < 4 ? cbS : cbR) + ((size_t)(cbi & 3) * NEC + j) * ED;
  float acc = 0.f;
  for (int k = 0; k < ED; k += 4) {
    float4 v = *(const float4*)(row + k);
    acc += v.x * v.x + v.y * v.y + v.z * v.z + v.w * v.w;
  }
  norms[cbi * NEC + j] = acc - 256.0f;   // exact shift (Sterbenz range)
}

// ---- f16 copy of codebooks (natural [cbi][j][k] layout) ----
__global__ void kConvH(const float* __restrict__ cbS, const float* __restrict__ cbR,
                       f16* __restrict__ cbH) {
  const int f   = blockIdx.x * 256 + threadIdx.x;   // 0..524287
  const int cbi = f >> 16;
  const int rem = f & 65535;
  const float v = (cbi < 4 ? cbS + ((size_t)cbi << 16) : cbR + ((size_t)(cbi - 4) << 16))[rem];
  cbH[f] = (f16)v;   // RTN
}

// packed key helpers: low 8 mantissa bits carry the codeword index
__device__ __forceinline__ float pk(float v, int j) {
  return __uint_as_float((__float_as_uint(v) & ~255u) | (unsigned)j);
}
__device__ __forceinline__ float unpv(float k) {
  return __uint_as_float(__float_as_uint(k) & ~255u);
}
__device__ __forceinline__ void ins3(float& s0, float& s1, float& s2, float k) {
  float t0 = fmaxf(s0, k); s0 = fminf(s0, k);
  float t1 = fmaxf(s1, t0); s1 = fminf(s1, t0);
  s2 = fminf(s2, t1);
}
__device__ __forceinline__ void mrg3(float& a0, float& a1, float& a2,
                                     float b0, float b1, float b2) {
  float x  = fmaxf(a0, b0);
  float c0 = fminf(a0, b0);
  float m1 = fminf(a1, b1), M1 = fmaxf(a1, b1);
  float c1 = fminf(fminf(x, a1), b1);
  float c2 = fminf(fminf(fmaxf(x, m1), M1), fminf(a2, b2));
  a0 = c0; a1 = c1; a2 = c2;
}

// ---- main fused RVQ kernel: 64 items/block, res in registers ----
// launch_bounds(256,3): 170-VGPR cap — res[64]+acc[4]+frags (~140) fits with NO
// spill; (256,4)'s 128 cap forced res to scratch (round 4: VGPR=64, +240MB fetch).
__global__ __launch_bounds__(256, 3)
void kMain(const float* __restrict__ x,
           const float* __restrict__ cbS,
           const float* __restrict__ cbR,
           const f16*  __restrict__ cbH,
           const float* __restrict__ norms,
           double* __restrict__ lossAcc,
           float* __restrict__ out) {
  __shared__ __align__(16) char  RhBuf[64 * 512];      // f16 residual image, swizzled (32 KB)
  __shared__ __align__(16) float keybuf[64][4][4];     // per-wave top-3 per item (4 KB)
  __shared__ float redS[4];

  const int tid   = threadIdx.x;
  const int lane  = tid & 63;
  const int w     = tid >> 6;       // wave: owns codewords [64w, 64w+64)
  const int it_o  = tid >> 2;       // owner item 0..63
  const int kq    = tid & 3;        // owner k-quarter
  const int b0    = blockIdx.x * 64;
  const int l15   = lane & 15;
  const int l4    = lane >> 4;

  float res[64];
  float lossReg = 0.f;

#pragma unroll 1
  for (int br = 0; br < 2; ++br) {
    const float* cbf32 = br ? cbR : cbS;

    // load residual = x[:, br*E .. br*E+E) slice into registers
    {
      const float* xp = x + (size_t)(b0 + it_o) * (2 * ED) + br * ED + kq * 64;
#pragma unroll
      for (int i = 0; i < 16; ++i) {
        float4 v = *(const float4*)(xp + 4 * i);
        res[4 * i + 0] = v.x; res[4 * i + 1] = v.y;
        res[4 * i + 2] = v.z; res[4 * i + 3] = v.w;
      }
    }

#pragma unroll 1
    for (int lev = 0; lev < NQL; ++lev) {
      const int cbi = br * 4 + lev;
      const float* nrm = norms + (size_t)cbi * NEC;

      // norm values for this wave's codeword columns (L1/L2-hot after level 0)
      float nv[4];
#pragma unroll
      for (int nt = 0; nt < 4; ++nt) nv[nt] = nrm[(w * 4 + nt) * 16 + l15];

      // convert res -> Rh (f16, RTN), swizzled rows of 512B
#pragma unroll
      for (int c = 0; c < 8; ++c) {
        f16x8 h;
#pragma unroll
        for (int u = 0; u < 8; ++u) h[u] = (f16)res[c * 8 + u];
        int off = it_o * 512 + kq * 128 + c * 16;
        off ^= (it_o & 7) << 4;
        *(f16x8*)&RhBuf[off] = h;
      }
      __syncthreads();   // barrier 1: Rh ready

      const f16* cbh = cbH + ((size_t)cbi << 16);

      // ---- GEMM + keys, one 16-item tile at a time (acc[4] live, not acc[4][4]) ----
#pragma unroll 1
      for (int mt = 0; mt < 4; ++mt) {
        f32x4 acc[4];
#pragma unroll
        for (int nt = 0; nt < 4; ++nt) { f32x4 z = {0.f, 0.f, 0.f, 0.f}; acc[nt] = z; }

        const int it = mt * 16 + l15;
#pragma unroll 2
        for (int ks = 0; ks < 8; ++ks) {
          // XOR applied to the FULL offset (write side identical) — do not hoist.
          const int offA = (it * 512 + ks * 64 + l4 * 16) ^ ((it & 7) << 4);
          f16x8 A = *(const f16x8*)&RhBuf[offA];
          f16x8 Bf[4];
#pragma unroll
          for (int nt = 0; nt < 4; ++nt) {
            int j = (w * 4 + nt) * 16 + l15;
            Bf[nt] = *(const f16x8*)&cbh[(size_t)j * ED + ks * 32 + l4 * 8];
          }
#pragma unroll
          for (int nt = 0; nt < 4; ++nt)
            acc[nt] = __builtin_amdgcn_mfma_f32_16x16x32_f16(A, Bf[nt], acc[nt], 0, 0, 0);
        }

        // keys + in-wave top-3 butterfly over the 16 l15-lanes (j-dimension)
#pragma unroll
        for (int r = 0; r < 4; ++r) {
          float s0 = FMAXV, s1 = FMAXV, s2 = FMAXV;
#pragma unroll
          for (int nt = 0; nt < 4; ++nt) {
            int j = (w * 4 + nt) * 16 + l15;
            ins3(s0, s1, s2, pk(fmaf(-2.f, acc[nt][r], nv[nt]), j));
          }
#pragma unroll
          for (int off = 1; off < 16; off <<= 1) {
            float b0k = __shfl_xor(s0, off), b1k = __shfl_xor(s1, off), b2k = __shfl_xor(s2, off);
            mrg3(s0, s1, s2, b0k, b1k, b2k);
          }
          if (l15 == r) {   // one writer per (l4, r) item (all lanes hold same result)
            float4 v; v.x = s0; v.y = s1; v.z = s2; v.w = FMAXV;
            *(float4*)&keybuf[mt * 16 + l4 * 4 + r][w][0] = v;
          }
        }
      }
      __syncthreads();   // barrier 2: keybuf ready (also: all GEMM reads of Rh done)

      // ---- cross-wave merge in the owner quad (no serial section, no LDS flags) ----
      int jm;
      {
        float4 v = *(const float4*)&keybuf[it_o][kq][0];
        float s0 = v.x, s1 = v.y, s2 = v.z;
        {
          float b0k = __shfl_xor(s0, 1), b1k = __shfl_xor(s1, 1), b2k = __shfl_xor(s2, 1);
          mrg3(s0, s1, s2, b0k, b1k, b2k);
          b0k = __shfl_xor(s0, 2); b1k = __shfl_xor(s1, 2); b2k = __shfl_xor(s2, 2);
          mrg3(s0, s1, s2, b0k, b1k, b2k);
        }
        jm = (int)(__float_as_uint(s0) & 255u);
        const float gap = unpv(s1) - unpv(s0);
        if (gap < TAU) {   // quad-uniform branch: exact fp32 rescore of top-3
          const int cand[3] = { jm,
                                (int)(__float_as_uint(s1) & 255u),
                                (int)(__float_as_uint(s2) & 255u) };
          float bestd = FMAXV; int bestj = 0;
#pragma unroll 1
          for (int cc = 0; cc < 3; ++cc) {
            const int j = cand[cc];
            const float* row = cbf32 + ((size_t)lev * NEC + j) * ED + kq * 64;
            float p = 0.f;
#pragma unroll
            for (int i = 0; i < 16; ++i) {
              float4 q = *(const float4*)(row + 4 * i);
              p = fmaf(res[4 * i + 0], q.x, p);
              p = fmaf(res[4 * i + 1], q.y, p);
              p = fmaf(res[4 * i + 2], q.z, p);
              p = fmaf(res[4 * i + 3], q.w, p);
            }
            p += __shfl_xor(p, 1);
            p += __shfl_xor(p, 2);
            const float d = fmaf(-2.f, p, nrm[j]);
            if (d < bestd || (d == bestd && j < bestj)) { bestd = d; bestj = j; }
          }
          jm = bestj;
        }
        if (kq == 0) {
          const size_t ioff = (br ? OFF_RIDX : OFF_SIDX) + (size_t)(b0 + it_o) * NQL + lev;
          out[ioff] = (float)jm;
        }
      }

      // ---- residual update + loss (exact reference rounding chain) ----
      {
        const float* crow = cbf32 + ((size_t)lev * NEC + jm) * ED + kq * 64;
#pragma unroll
        for (int i = 0; i < 16; ++i) {
          float4 q = *(const float4*)(crow + 4 * i);
#pragma unroll
          for (int u = 0; u < 4; ++u) {
            float cv = (u == 0 ? q.x : u == 1 ? q.y : u == 2 ? q.z : q.w);
            float r  = res[4 * i + u];
            float dd = cv - r;
            lossReg = fmaf(dd, dd, lossReg);
            float xr = r + dd;      // straight-through x_res
            res[4 * i + u] = r - xr;
          }
        }
      }
    }

    // x_q = x - res_final
    {
      const float* xp = x + (size_t)(b0 + it_o) * (2 * ED) + br * ED + kq * 64;
      float* op = out + (br ? OFF_REC : 0) + (size_t)(b0 + it_o) * ED + kq * 64;
#pragma unroll
      for (int i = 0; i < 16; ++i) {
        float4 xv = *(const float4*)(xp + 4 * i);
        float4 o;
        o.x = xv.x - res[4 * i + 0];
        o.y = xv.y - res[4 * i + 1];
        o.z = xv.z - res[4 * i + 2];
        o.w = xv.w - res[4 * i + 3];
        *(float4*)(op + 4 * i) = o;
      }
    }
  }

  // ---- loss: one wave-reduce + one atomic per block, once per kernel ----
#pragma unroll
  for (int d = 1; d < 64; d <<= 1) lossReg += __shfl_xor(lossReg, d);
  if (lane == 0) redS[w] = lossReg;
  __syncthreads();
  if (tid == 0)
    atomicAdd(&lossAcc[0], (double)((redS[0] + redS[1]) + (redS[2] + redS[3])));
}

// ---- finalize scalar loss ----
__global__ void kFin(const double* __restrict__ lossAcc, float* __restrict__ out) {
  if (blockIdx.x == 0 && threadIdx.x == 0) {
    out[OFF_LOSS] = (float)(lossAcc[0] * 1.25 / ((double)NB * ED) / 8.0);
  }
}

extern "C" void kernel_launch(void* const* d_in, const int* in_sizes, int n_in,
                              void* d_out, int out_size, void* d_ws, size_t ws_size,
                              hipStream_t stream) {
  const float* x   = (const float*)d_in[0];
  const float* cbS = (const float*)d_in[1];
  const float* cbR = (const float*)d_in[2];
  float* out = (float*)d_out;
  char*  ws  = (char*)d_ws;

  double* lossAcc = (double*)(ws + WS_LOSS);
  float*  norms   = (float*)(ws + WS_NORM);
  f16*    cbH     = (f16*)(ws + WS_CBH);

  hipLaunchKernelGGL(kPrep,  dim3(8),    dim3(256), 0, stream, cbS, cbR, norms, lossAcc);
  hipLaunchKernelGGL(kConvH, dim3(2048), dim3(256), 0, stream, cbS, cbR, cbH);
  hipLaunchKernelGGL(kMain,  dim3(NB / 64), dim3(256), 0, stream,
                     x, cbS, cbR, cbH, norms, lossAcc, out);
  hipLaunchKernelGGL(kFin,   dim3(1),    dim3(64),  0, stream, lossAcc, out);
}

// Round 6
// 580.775 us; speedup vs baseline: 2.3848x; 2.0937x over previous
//
#include <hip/hip_runtime.h>
#include <hip/hip_bf16.h>
#include <hip/hip_fp16.h>
#include <cstdint>
#include <cstddef>

#define NB   131072   // items
#define ED   256      // e_dim
#define NQL  4        // levels
#define NEC  256      // codebook entries

typedef _Float16 f16;
typedef f16  f16x8 __attribute__((ext_vector_type(8)));
typedef float f32x4 __attribute__((ext_vector_type(4)));

static constexpr float FMAXV = 3.402823466e+38f;
static constexpr float TAU   = 0.15625f;   // rescore gate on approx top-2 gap

static constexpr size_t OFF_REC  = (size_t)NB * ED;
static constexpr size_t OFF_LOSS = 2 * (size_t)NB * ED;
static constexpr size_t OFF_SIDX = OFF_LOSS + 1;
static constexpr size_t OFF_RIDX = OFF_SIDX + (size_t)NB * NQL;

// workspace layout (bytes)
static constexpr size_t WS_LOSS = 0;                      // 8 doubles
static constexpr size_t WS_NORM = 256;                    // 8*256 f32 (norm - 256)
static constexpr size_t WS_CBH  = 256 + 8 * 256 * 4;      // 8448; 8*256*256 f16 (1 MB)

// ---- prep: zero loss accumulator + codebook row norms (pre-shifted by -256) ----
__global__ void kPrep(const float* __restrict__ cbS, const float* __restrict__ cbR,
                      float* __restrict__ norms, double* __restrict__ lossAcc) {
  const int cbi = blockIdx.x;    // 0..7
  const int j   = threadIdx.x;   // 0..255
  if (cbi == 0 && j < 8) lossAcc[j] = 0.0;
  const float* row = (cbi < 4 ? cbS : cbR) + ((size_t)(cbi & 3) * NEC + j) * ED;
  float acc = 0.f;
  for (int k = 0; k < ED; k += 4) {
    float4 v = *(const float4*)(row + k);
    acc += v.x * v.x + v.y * v.y + v.z * v.z + v.w * v.w;
  }
  norms[cbi * NEC + j] = acc - 256.0f;   // exact shift (Sterbenz range)
}

// ---- f16 copy of codebooks (natural [cbi][j][k] layout) ----
__global__ void kConvH(const float* __restrict__ cbS, const float* __restrict__ cbR,
                       f16* __restrict__ cbH) {
  const int f   = blockIdx.x * 256 + threadIdx.x;   // 0..524287
  const int cbi = f >> 16;
  const int rem = f & 65535;
  const float v = (cbi < 4 ? cbS + ((size_t)cbi << 16) : cbR + ((size_t)(cbi - 4) << 16))[rem];
  cbH[f] = (f16)v;   // RTN
}

// packed key helpers: low 8 mantissa bits carry the codeword index
__device__ __forceinline__ float pk(float v, int j) {
  return __uint_as_float((__float_as_uint(v) & ~255u) | (unsigned)j);
}
__device__ __forceinline__ float unpv(float k) {
  return __uint_as_float(__float_as_uint(k) & ~255u);
}
__device__ __forceinline__ void ins3(float& s0, float& s1, float& s2, float k) {
  float t0 = fmaxf(s0, k); s0 = fminf(s0, k);
  float t1 = fmaxf(s1, t0); s1 = fminf(s1, t0);
  s2 = fminf(s2, t1);
}
__device__ __forceinline__ void mrg3(float& a0, float& a1, float& a2,
                                     float b0, float b1, float b2) {
  float x  = fmaxf(a0, b0);
  float c0 = fminf(a0, b0);
  float m1 = fminf(a1, b1), M1 = fmaxf(a1, b1);
  float c1 = fminf(fminf(x, a1), b1);
  float c2 = fminf(fminf(fmaxf(x, m1), M1), fminf(a2, b2));
  a0 = c0; a1 = c1; a2 = c2;
}

// ---- main fused RVQ kernel: 64 items/block, res in registers, 2 blocks/CU ----
// acc[4][4] (full 64x64 tile per wave, 16 MFMA per ks, B fetched ONCE per level
// per wave). Operand-swapped MFMA: D[j][item] so per-lane j-reduction is
// in-thread (16 values) + 2 shuffle steps, vs 4 steps x 4r x 4mt before.
__global__ __launch_bounds__(256, 2)
void kMain(const float* __restrict__ x,
           const float* __restrict__ cbS,
           const float* __restrict__ cbR,
           const f16*  __restrict__ cbH,
           const float* __restrict__ norms,
           double* __restrict__ lossAcc,
           float* __restrict__ out) {
  __shared__ __align__(16) char  RhBuf[64 * 512];      // f16 residual image, swizzled (32 KB)
  __shared__ __align__(16) float keybuf[64][4][4];     // per-wave top-3 per item (4 KB)
  __shared__ float redS[4];

  const int tid   = threadIdx.x;
  const int lane  = tid & 63;
  const int w     = tid >> 6;       // wave: owns codewords [64w, 64w+64)
  const int it_o  = tid >> 2;       // owner item 0..63
  const int kq    = tid & 3;        // owner k-quarter
  const int b0    = blockIdx.x * 64;
  const int l15   = lane & 15;
  const int l4    = lane >> 4;

  float res[64];
  float lossReg = 0.f;

#pragma unroll 1
  for (int br = 0; br < 2; ++br) {
    const float* cbf32 = br ? cbR : cbS;

    // load residual = x[:, br*E .. br*E+E) slice into registers
    {
      const float* xp = x + (size_t)(b0 + it_o) * (2 * ED) + br * ED + kq * 64;
#pragma unroll
      for (int i = 0; i < 16; ++i) {
        float4 v = *(const float4*)(xp + 4 * i);
        res[4 * i + 0] = v.x; res[4 * i + 1] = v.y;
        res[4 * i + 2] = v.z; res[4 * i + 3] = v.w;
      }
    }

#pragma unroll 1
    for (int lev = 0; lev < NQL; ++lev) {
      const int cbi = br * 4 + lev;
      const float* nrm = norms + (size_t)cbi * NEC;

      // convert res -> Rh (f16, RTN), swizzled rows of 512B
#pragma unroll
      for (int c = 0; c < 8; ++c) {
        f16x8 h;
#pragma unroll
        for (int u = 0; u < 8; ++u) h[u] = (f16)res[c * 8 + u];
        int off = it_o * 512 + kq * 128 + c * 16;
        off ^= (it_o & 7) << 4;
        *(f16x8*)&RhBuf[off] = h;
      }
      __syncthreads();   // barrier 1: Rh ready

      const f16* cbh = cbH + ((size_t)cbi << 16);

      // ---- GEMM: full 64(item) x 64(j) tile per wave, D[j][item] ----
      f32x4 acc[4][4];
#pragma unroll
      for (int mt = 0; mt < 4; ++mt)
#pragma unroll
        for (int nt = 0; nt < 4; ++nt) { f32x4 z = {0.f, 0.f, 0.f, 0.f}; acc[mt][nt] = z; }

#pragma unroll 2
      for (int ks = 0; ks < 8; ++ks) {
        f16x8 A[4], Bf[4];
#pragma unroll
        for (int mt = 0; mt < 4; ++mt) {
          const int it = mt * 16 + l15;
          // XOR applied to the FULL offset (write side identical) — do not hoist.
          const int offA = (it * 512 + ks * 64 + l4 * 16) ^ ((it & 7) << 4);
          A[mt] = *(const f16x8*)&RhBuf[offA];
        }
#pragma unroll
        for (int nt = 0; nt < 4; ++nt) {
          const int j = (w * 4 + nt) * 16 + l15;
          Bf[nt] = *(const f16x8*)&cbh[(size_t)j * ED + ks * 32 + l4 * 8];
        }
#pragma unroll
        for (int mt = 0; mt < 4; ++mt)
#pragma unroll
          for (int nt = 0; nt < 4; ++nt)
            // operand swap: codebook as A (rows=j), residual as B (cols=item)
            acc[mt][nt] = __builtin_amdgcn_mfma_f32_16x16x32_f16(Bf[nt], A[mt], acc[mt][nt], 0, 0, 0);
      }

      // ---- argmin: lane holds 16 j-values (nt x r) for item = mt*16+l15 ----
      float4 nvq[4];
#pragma unroll
      for (int nt = 0; nt < 4; ++nt)
        nvq[nt] = *(const float4*)&nrm[(w * 4 + nt) * 16 + l4 * 4];

#pragma unroll
      for (int mt = 0; mt < 4; ++mt) {
        float s0 = FMAXV, s1 = FMAXV, s2 = FMAXV;
#pragma unroll
        for (int nt = 0; nt < 4; ++nt) {
#pragma unroll
          for (int r = 0; r < 4; ++r) {
            const int j = (w * 4 + nt) * 16 + l4 * 4 + r;
            const float nr = (r == 0 ? nvq[nt].x : r == 1 ? nvq[nt].y
                              : r == 2 ? nvq[nt].z : nvq[nt].w);
            ins3(s0, s1, s2, pk(fmaf(-2.f, acc[mt][nt][r], nr), j));
          }
        }
        // merge the 4 l4-groups (disjoint j-subsets, same item): xor 16, 32
        {
          float b0k = __shfl_xor(s0, 16), b1k = __shfl_xor(s1, 16), b2k = __shfl_xor(s2, 16);
          mrg3(s0, s1, s2, b0k, b1k, b2k);
          b0k = __shfl_xor(s0, 32); b1k = __shfl_xor(s1, 32); b2k = __shfl_xor(s2, 32);
          mrg3(s0, s1, s2, b0k, b1k, b2k);
        }
        if (l4 == 0) {   // 16 writers per mt
          float4 v; v.x = s0; v.y = s1; v.z = s2; v.w = FMAXV;
          *(float4*)&keybuf[mt * 16 + l15][w][0] = v;
        }
      }
      __syncthreads();   // barrier 2: keybuf ready (also: Rh reads done)

      // ---- cross-wave merge in the owner quad ----
      int jm;
      {
        float4 v = *(const float4*)&keybuf[it_o][kq][0];
        float s0 = v.x, s1 = v.y, s2 = v.z;
        {
          float b0k = __shfl_xor(s0, 1), b1k = __shfl_xor(s1, 1), b2k = __shfl_xor(s2, 1);
          mrg3(s0, s1, s2, b0k, b1k, b2k);
          b0k = __shfl_xor(s0, 2); b1k = __shfl_xor(s1, 2); b2k = __shfl_xor(s2, 2);
          mrg3(s0, s1, s2, b0k, b1k, b2k);
        }
        jm = (int)(__float_as_uint(s0) & 255u);
        const float gap = unpv(s1) - unpv(s0);
        if (gap < TAU) {   // quad-uniform branch: exact fp32 rescore of top-3
          const int cand[3] = { jm,
                                (int)(__float_as_uint(s1) & 255u),
                                (int)(__float_as_uint(s2) & 255u) };
          float bestd = FMAXV; int bestj = 0;
#pragma unroll 1
          for (int cc = 0; cc < 3; ++cc) {
            const int j = cand[cc];
            const float* row = cbf32 + ((size_t)lev * NEC + j) * ED + kq * 64;
            float p = 0.f;
#pragma unroll
            for (int i = 0; i < 16; ++i) {
              float4 q = *(const float4*)(row + 4 * i);
              p = fmaf(res[4 * i + 0], q.x, p);
              p = fmaf(res[4 * i + 1], q.y, p);
              p = fmaf(res[4 * i + 2], q.z, p);
              p = fmaf(res[4 * i + 3], q.w, p);
            }
            p += __shfl_xor(p, 1);
            p += __shfl_xor(p, 2);
            const float d = fmaf(-2.f, p, nrm[j]);
            if (d < bestd || (d == bestd && j < bestj)) { bestd = d; bestj = j; }
          }
          jm = bestj;
        }
        if (kq == 0) {
          const size_t ioff = (br ? OFF_RIDX : OFF_SIDX) + (size_t)(b0 + it_o) * NQL + lev;
          out[ioff] = (float)jm;
        }
      }

      // ---- residual update + loss (exact reference rounding chain) ----
      {
        const float* crow = cbf32 + ((size_t)lev * NEC + jm) * ED + kq * 64;
#pragma unroll
        for (int i = 0; i < 16; ++i) {
          float4 q = *(const float4*)(crow + 4 * i);
#pragma unroll
          for (int u = 0; u < 4; ++u) {
            float cv = (u == 0 ? q.x : u == 1 ? q.y : u == 2 ? q.z : q.w);
            float r  = res[4 * i + u];
            float dd = cv - r;
            lossReg = fmaf(dd, dd, lossReg);
            float xr = r + dd;      // straight-through x_res
            res[4 * i + u] = r - xr;
          }
        }
      }
    }

    // x_q = x - res_final
    {
      const float* xp = x + (size_t)(b0 + it_o) * (2 * ED) + br * ED + kq * 64;
      float* op = out + (br ? OFF_REC : 0) + (size_t)(b0 + it_o) * ED + kq * 64;
#pragma unroll
      for (int i = 0; i < 16; ++i) {
        float4 xv = *(const float4*)(xp + 4 * i);
        float4 o;
        o.x = xv.x - res[4 * i + 0];
        o.y = xv.y - res[4 * i + 1];
        o.z = xv.z - res[4 * i + 2];
        o.w = xv.w - res[4 * i + 3];
        *(float4*)(op + 4 * i) = o;
      }
    }
  }

  // ---- loss: one wave-reduce + one atomic per block, once per kernel ----
#pragma unroll
  for (int d = 1; d < 64; d <<= 1) lossReg += __shfl_xor(lossReg, d);
  if (lane == 0) redS[w] = lossReg;
  __syncthreads();
  if (tid == 0)
    atomicAdd(&lossAcc[0], (double)((redS[0] + redS[1]) + (redS[2] + redS[3])));
}

// ---- finalize scalar loss ----
__global__ void kFin(const double* __restrict__ lossAcc, float* __restrict__ out) {
  if (blockIdx.x == 0 && threadIdx.x == 0) {
    out[OFF_LOSS] = (float)(lossAcc[0] * 1.25 / ((double)NB * ED) / 8.0);
  }
}

extern "C" void kernel_launch(void* const* d_in, const int* in_sizes, int n_in,
                              void* d_out, int out_size, void* d_ws, size_t ws_size,
                              hipStream_t stream) {
  const float* x   = (const float*)d_in[0];
  const float* cbS = (const float*)d_in[1];
  const float* cbR = (const float*)d_in[2];
  float* out = (float*)d_out;
  char*  ws  = (char*)d_ws;

  double* lossAcc = (double*)(ws + WS_LOSS);
  float*  norms   = (float*)(ws + WS_NORM);
  f16*    cbH     = (f16*)(ws + WS_CBH);

  hipLaunchKernelGGL(kPrep,  dim3(8),    dim3(256), 0, stream, cbS, cbR, norms, lossAcc);
  hipLaunchKernelGGL(kConvH, dim3(2048), dim3(256), 0, stream, cbS, cbR, cbH);
  hipLaunchKernelGGL(kMain,  dim3(NB / 64), dim3(256), 0, stream,
                     x, cbS, cbR, cbH, norms, lossAcc, out);
  hipLaunchKernelGGL(kFin,   dim3(1),    dim3(64),  0, stream, lossAcc, out);
}